// Round 3
// baseline (1997.678 us; speedup 1.0000x reference)
//
#include <hip/hip_runtime.h>

#define NNODE 100000
#define NCLS  50000
#define NEDGE 400000
#define NDIM  43
#define CDIM  2
#define HID   128
#define NHEAD 4
#define CHN   32
#define NLAY  4

// ---------------------------------------------------------------------------
// Generic small-K projection (used for class proj, K=2).
__global__ void proj_kernel(const float* __restrict__ X, const float* __restrict__ W,
                            const float* __restrict__ B, float* __restrict__ Y,
                            int nrows, int K) {
  int t = blockIdx.x * blockDim.x + threadIdx.x;
  if (t >= nrows * HID) return;
  int i = t >> 7, j = t & (HID - 1);
  float acc = B[j];
  for (int k = 0; k < K; ++k)
    acc = fmaf(X[i * K + k], W[k * HID + j], acc);
  Y[t] = acc;
}

// ---------------------------------------------------------------------------
// Node projection, K=43, LDS-tiled. 32 rows/block, 256 threads, 4x4 per thread.
__global__ __launch_bounds__(256) void proj_node(const float* __restrict__ X,
                                                 const float* __restrict__ W,
                                                 const float* __restrict__ B,
                                                 float* __restrict__ Y) {
  __shared__ float Ws[NDIM][HID];   // 22016 B, [k][j]
  __shared__ float Xs[32][NDIM];    // 5504 B,  [r][k]
  const int tid = threadIdx.x;
  const int row0 = blockIdx.x * 32;

  for (int i = tid; i < NDIM * (HID / 4); i += 256) {
    int k = i >> 5, j4 = (i & 31) << 2;
    *(float4*)&Ws[k][j4] = *(const float4*)&W[(size_t)k * HID + j4];
  }
  const float* Xb = X + (size_t)row0 * NDIM;
  for (int i = tid; i < 32 * NDIM; i += 256) ((float*)Xs)[i] = Xb[i];
  __syncthreads();

  const int cg = tid & 31, rg = tid >> 5;
  const int j0 = cg * 4, r0 = rg * 4;

  float acc[4][4];
#pragma unroll
  for (int rr = 0; rr < 4; ++rr)
#pragma unroll
    for (int cc = 0; cc < 4; ++cc) acc[rr][cc] = 0.f;

#pragma unroll 4
  for (int k = 0; k < NDIM; ++k) {
    const float4 w = *(const float4*)&Ws[k][j0];
    const float wv[4] = {w.x, w.y, w.z, w.w};
    const float xx[4] = {Xs[r0 + 0][k], Xs[r0 + 1][k], Xs[r0 + 2][k], Xs[r0 + 3][k]};
#pragma unroll
    for (int rr = 0; rr < 4; ++rr)
#pragma unroll
      for (int cc = 0; cc < 4; ++cc)
        acc[rr][cc] = fmaf(xx[rr], wv[cc], acc[rr][cc]);
  }

  const float4 bv = *(const float4*)&B[j0];
  const float bb[4] = {bv.x, bv.y, bv.z, bv.w};
#pragma unroll
  for (int rr = 0; rr < 4; ++rr) {
    float4 o = make_float4(acc[rr][0] + bb[0], acc[rr][1] + bb[1],
                           acc[rr][2] + bb[2], acc[rr][3] + bb[3]);
    *(float4*)&Y[(size_t)(row0 + r0 + rr) * HID + j0] = o;
  }
}

// ---------------------------------------------------------------------------
// Y[r][j] = B[j] + sum_k X[r][k]*W[k][j],  X f32 [nrows][128], W f32 [128][128].
// v3: wave owns 16 uniform rows (scalar X via s_load), lanes span 128 cols.
//  - X: wave-uniform scalar loads (s_load_dwordx4) -> scalar pipe, no LDS.
//  - W: staged 32-k chunk in LDS; one conflict-free ds_read_b64 per k per wave.
//  - FMA: acc(vgpr) += s_x(sgpr) * w(vgpr)  -> VALU-bound.
__global__ __launch_bounds__(256) void gemm128(const float* __restrict__ X,
                                               const float* __restrict__ W,
                                               const float* __restrict__ B,
                                               float* __restrict__ Y, int nrows) {
  __shared__ float Ws[32][HID];   // 16 KB, [k][j]
  const int tid = threadIdx.x;
  const int row0 = blockIdx.x * 64;
  const int lane = tid & 63;
  const int rgu = __builtin_amdgcn_readfirstlane(tid >> 6);  // wave id (uniform)
  const int r0 = rgu * 16;
  const int j0 = lane * 2;

  float acc[16][2];
#pragma unroll
  for (int rr = 0; rr < 16; ++rr) { acc[rr][0] = 0.f; acc[rr][1] = 0.f; }

  // uniform, clamped row indices (scalar reads never fault; stores are guarded)
  int grow[16];
#pragma unroll
  for (int rr = 0; rr < 16; ++rr) {
    int gr = row0 + r0 + rr;
    grow[rr] = gr < nrows ? gr : nrows - 1;
  }

  for (int kc = 0; kc < 4; ++kc) {
    const int k0 = kc * 32;
    // stage W chunk: 32x128 floats = 1024 float4, 4 per thread, coalesced
    for (int i = tid; i < 1024; i += 256) {
      int k = i >> 5, j4 = (i & 31) << 2;
      *(float4*)&Ws[k][j4] = *(const float4*)&W[(size_t)(k0 + k) * HID + j4];
    }
    __syncthreads();

    for (int ks = 0; ks < 32; ks += 4) {
      // scalar X: 16 rows x 4 k (uniform addresses -> s_load_dwordx4)
      float xs[16][4];
#pragma unroll
      for (int rr = 0; rr < 16; ++rr) {
        const float4 xv = *(const float4*)&X[(size_t)grow[rr] * HID + k0 + ks];
        xs[rr][0] = xv.x; xs[rr][1] = xv.y; xs[rr][2] = xv.z; xs[rr][3] = xv.w;
      }
#pragma unroll
      for (int kk = 0; kk < 4; ++kk) {
        const float2 w = *(const float2*)&Ws[ks + kk][j0];
#pragma unroll
        for (int rr = 0; rr < 16; ++rr) {
          acc[rr][0] = fmaf(xs[rr][kk], w.x, acc[rr][0]);
          acc[rr][1] = fmaf(xs[rr][kk], w.y, acc[rr][1]);
        }
      }
    }
    __syncthreads();
  }

  const float2 bv = *(const float2*)&B[j0];
#pragma unroll
  for (int rr = 0; rr < 16; ++rr) {
    int gr = row0 + r0 + rr;
    if (gr < nrows) {
      float2 o = make_float2(acc[rr][0] + bv.x, acc[rr][1] + bv.y);
      *(float2*)&Y[(size_t)gr * HID + j0] = o;
    }
  }
}

// ---------------------------------------------------------------------------
// CSR build: histogram -> scan -> scatter
__global__ void hist_kernel(const int* __restrict__ dst, int* __restrict__ cnt) {
  int e = blockIdx.x * 256 + threadIdx.x;
  if (e < NEDGE) atomicAdd(&cnt[dst[e]], 1);
}

__global__ __launch_bounds__(256) void scan_blocks(const int* __restrict__ cnt,
                                                   int* __restrict__ pre,
                                                   int* __restrict__ bsum, int n) {
  __shared__ int sdata[256];
  const int b = blockIdx.x, t = threadIdx.x;
  const int base = b * 1024 + t * 4;
  int v[4], s = 0;
#pragma unroll
  for (int q = 0; q < 4; ++q) {
    int i = base + q;
    v[q] = (i < n) ? cnt[i] : 0;
    s += v[q];
  }
  sdata[t] = s;
  __syncthreads();
  for (int off = 1; off < 256; off <<= 1) {
    int y = (t >= off) ? sdata[t - off] : 0;
    __syncthreads();
    sdata[t] += y;
    __syncthreads();
  }
  int run = sdata[t] - s;  // exclusive prefix of thread sums
  if (t == 255) bsum[b] = sdata[255];
#pragma unroll
  for (int q = 0; q < 4; ++q) {
    int i = base + q;
    if (i < n) pre[i] = run;
    run += v[q];
  }
}

// single block; nb <= 128
__global__ __launch_bounds__(128) void scan_partials(int* __restrict__ bsum, int nb) {
  __shared__ int sd[128];
  int t = threadIdx.x;
  int v = (t < nb) ? bsum[t] : 0;
  sd[t] = v;
  __syncthreads();
  for (int off = 1; off < 128; off <<= 1) {
    int y = (t >= off) ? sd[t - off] : 0;
    __syncthreads();
    sd[t] += y;
    __syncthreads();
  }
  if (t < nb) bsum[t] = sd[t] - v;  // exclusive
}

__global__ void finalize_rowptr(const int* __restrict__ pre, const int* __restrict__ bsum,
                                int* __restrict__ rowptr, int n) {
  int i = blockIdx.x * 256 + threadIdx.x;
  if (i < n) rowptr[i] = pre[i] + bsum[i >> 10];
  if (i == 0) rowptr[n] = NEDGE;
}

__global__ void scatter_csr(const int* __restrict__ src, const int* __restrict__ dst,
                            const int* __restrict__ rowptr, int* __restrict__ cursor,
                            int* __restrict__ csr_src) {
  int e = blockIdx.x * 256 + threadIdx.x;
  if (e >= NEDGE) return;
  int d = dst[e];
  int p = atomicAdd(&cursor[d], 1);
  csr_src[rowptr[d] + p] = src[e];
}

// ---------------------------------------------------------------------------
// Fused per-dst GATv2: persistent, one wave (64 lanes x float2) per dst row.
__global__ __launch_bounds__(256) void gat_dst(float* __restrict__ x,          // [n_dst][128] inout
                                               const float* __restrict__ xl,   // [n_src][128]
                                               const float* __restrict__ xr,   // [n_dst][128]
                                               const int* __restrict__ rowptr,
                                               const int* __restrict__ csr_src,
                                               const float* __restrict__ att,  // [128]
                                               const float* __restrict__ bias,
                                               const float* __restrict__ g,
                                               const float* __restrict__ b,
                                               int n_dst) {
  const int wave = threadIdx.x >> 6;     // 0..3
  const int lane = threadIdx.x & 63;
  const int j = lane * 2;                // channels j, j+1; head = j>>5 = lane>>4

  const float2 attv = *(const float2*)&att[j];
  const float2 bias2 = *(const float2*)&bias[j];
  const float2 g2 = *(const float2*)&g[j];
  const float2 b2 = *(const float2*)&b[j];

  const int stride = gridDim.x * 4;
  for (int d = blockIdx.x * 4 + wave; d < n_dst; d += stride) {
    const float2 xrv = *(const float2*)&xr[(size_t)d * HID + j];
    const int e0 = rowptr[d], e1 = rowptr[d + 1];

    float2 acc = make_float2(0.f, 0.f);
    float den = 0.f;
    int idx = e0;
    for (; idx + 1 < e1; idx += 2) {
      const int s0 = csr_src[idx];
      const int s1 = csr_src[idx + 1];
      const float2 v0 = *(const float2*)&xl[(size_t)s0 * HID + j];
      const float2 v1 = *(const float2*)&xl[(size_t)s1 * HID + j];
      {
        float m0 = v0.x + xrv.x; m0 = m0 > 0.f ? m0 : 0.2f * m0;
        float m1 = v0.y + xrv.y; m1 = m1 > 0.f ? m1 : 0.2f * m1;
        float p = fmaf(attv.x, m0, attv.y * m1);
        p += __shfl_xor(p, 8); p += __shfl_xor(p, 4);
        p += __shfl_xor(p, 2); p += __shfl_xor(p, 1);
        float e_ = __expf(p);
        acc.x = fmaf(e_, v0.x, acc.x);
        acc.y = fmaf(e_, v0.y, acc.y);
        den += e_;
      }
      {
        float m0 = v1.x + xrv.x; m0 = m0 > 0.f ? m0 : 0.2f * m0;
        float m1 = v1.y + xrv.y; m1 = m1 > 0.f ? m1 : 0.2f * m1;
        float p = fmaf(attv.x, m0, attv.y * m1);
        p += __shfl_xor(p, 8); p += __shfl_xor(p, 4);
        p += __shfl_xor(p, 2); p += __shfl_xor(p, 1);
        float e_ = __expf(p);
        acc.x = fmaf(e_, v1.x, acc.x);
        acc.y = fmaf(e_, v1.y, acc.y);
        den += e_;
      }
    }
    if (idx < e1) {
      const int s0 = csr_src[idx];
      const float2 v0 = *(const float2*)&xl[(size_t)s0 * HID + j];
      float m0 = v0.x + xrv.x; m0 = m0 > 0.f ? m0 : 0.2f * m0;
      float m1 = v0.y + xrv.y; m1 = m1 > 0.f ? m1 : 0.2f * m1;
      float p = fmaf(attv.x, m0, attv.y * m1);
      p += __shfl_xor(p, 8); p += __shfl_xor(p, 4);
      p += __shfl_xor(p, 2); p += __shfl_xor(p, 1);
      float e_ = __expf(p);
      acc.x = fmaf(e_, v0.x, acc.x);
      acc.y = fmaf(e_, v0.y, acc.y);
      den += e_;
    }

    float2 outv = make_float2(0.f, 0.f);
    if (e1 > e0) { outv.x = acc.x / den; outv.y = acc.y / den; }

    const float2 xv = *(const float2*)&x[(size_t)d * HID + j];
    float vx = xv.x + outv.x + bias2.x;
    float vy = xv.y + outv.y + bias2.y;

    // LayerNorm across the wave (64 lanes x 2 channels = 128)
    float s1 = vx + vy;
    float s2 = vx * vx + vy * vy;
#pragma unroll
    for (int off = 32; off > 0; off >>= 1) {
      s1 += __shfl_xor(s1, off);
      s2 += __shfl_xor(s2, off);
    }
    const float mu = s1 * (1.0f / HID);
    const float var = s2 * (1.0f / HID) - mu * mu;
    const float inv = rsqrtf(var + 1e-5f);
    float2 o = make_float2((vx - mu) * inv * g2.x + b2.x,
                           (vy - mu) * inv * g2.y + b2.y);
    *(float2*)&x[(size_t)d * HID + j] = o;
  }
}

// ---------------------------------------------------------------------------
__global__ void colsum(const float* __restrict__ xc, float* __restrict__ acc) {
  int j = threadIdx.x;  // 128 threads
  int per = (NCLS + gridDim.x - 1) / gridDim.x;
  int r0 = blockIdx.x * per;
  int r1 = min(r0 + per, NCLS);
  float s = 0.f;
  for (int r = r0; r < r1; ++r) s += xc[(size_t)r * HID + j];
  atomicAdd(&acc[j], s);
}

__global__ void final_out(const float* __restrict__ acc, float* __restrict__ out) {
  int j = threadIdx.x;
  out[j] = acc[j] * (1.0f / NCLS);
}

// ---------------------------------------------------------------------------
extern "C" void kernel_launch(void* const* d_in, const int* in_sizes, int n_in,
                              void* d_out, int out_size, void* d_ws, size_t ws_size,
                              hipStream_t stream) {
  (void)in_sizes; (void)n_in; (void)out_size; (void)ws_size;
  const float* x_node     = (const float*)d_in[0];
  const float* x_class    = (const float*)d_in[1];
  const int* member_src   = (const int*)d_in[2];
  const int* member_dst   = (const int*)d_in[3];
  const int* contains_src = (const int*)d_in[4];
  const int* contains_dst = (const int*)d_in[5];
  const float* npw = (const float*)d_in[6];
  const float* npb = (const float*)d_in[7];
  const float* cpw = (const float*)d_in[8];
  const float* cpb = (const float*)d_in[9];
  const float* n2c_wl   = (const float*)d_in[10];
  const float* n2c_bl   = (const float*)d_in[11];
  const float* n2c_wr   = (const float*)d_in[12];
  const float* n2c_br   = (const float*)d_in[13];
  const float* n2c_att  = (const float*)d_in[14];
  const float* n2c_bias = (const float*)d_in[15];
  const float* c2n_wl   = (const float*)d_in[16];
  const float* c2n_bl   = (const float*)d_in[17];
  const float* c2n_wr   = (const float*)d_in[18];
  const float* c2n_br   = (const float*)d_in[19];
  const float* c2n_att  = (const float*)d_in[20];
  const float* c2n_bias = (const float*)d_in[21];
  const float* ln_cg = (const float*)d_in[22];
  const float* ln_cb = (const float*)d_in[23];
  const float* ln_ng = (const float*)d_in[24];
  const float* ln_nb = (const float*)d_in[25];

  float* ws  = (float*)d_ws;
  float* xn  = ws;                                  // NNODE*128
  float* xc  = xn  + (size_t)NNODE * HID;           // NCLS*128
  float* xl  = xc  + (size_t)NCLS * HID;            // NNODE*128
  float* xr  = xl  + (size_t)NNODE * HID;           // NNODE*128
  float* acc = xr  + (size_t)NNODE * HID;           // 128
  int* ip        = (int*)(acc + 128);
  int* rowptr_c  = ip;                              // NCLS+1
  int* csr_c     = rowptr_c + (NCLS + 1);           // NEDGE
  int* rowptr_n  = csr_c + NEDGE;                   // NNODE+1
  int* csr_n     = rowptr_n + (NNODE + 1);          // NEDGE
  int* cnt       = csr_n + NEDGE;                   // NNODE (max)
  int* cursor    = cnt + NNODE;                     // NNODE
  int* pre       = cursor + NNODE;                  // NNODE
  int* bsum      = pre + NNODE;                     // 128

  const int EB = (NEDGE + 255) / 256;
  const int GAT_BLOCKS = 2048;  // persistent: 2048 blocks x 4 waves

  // ---- initial projections ----
  proj_node<<<NNODE / 32, 256, 0, stream>>>(x_node, npw, npb, xn);
  proj_kernel<<<(NCLS * HID + 255) / 256, 256, 0, stream>>>(x_class, cpw, cpb, xc, NCLS, CDIM);

  // ---- CSR build: member (dst=class) ----
  hipMemsetAsync(cnt, 0, NCLS * sizeof(int), stream);
  hipMemsetAsync(cursor, 0, NCLS * sizeof(int), stream);
  hist_kernel<<<EB, 256, 0, stream>>>(member_dst, cnt);
  scan_blocks<<<(NCLS + 1023) / 1024, 256, 0, stream>>>(cnt, pre, bsum, NCLS);
  scan_partials<<<1, 128, 0, stream>>>(bsum, (NCLS + 1023) / 1024);
  finalize_rowptr<<<(NCLS + 255) / 256, 256, 0, stream>>>(pre, bsum, rowptr_c, NCLS);
  scatter_csr<<<EB, 256, 0, stream>>>(member_src, member_dst, rowptr_c, cursor, csr_c);

  // ---- CSR build: contains (dst=node) ----
  hipMemsetAsync(cnt, 0, NNODE * sizeof(int), stream);
  hipMemsetAsync(cursor, 0, NNODE * sizeof(int), stream);
  hist_kernel<<<EB, 256, 0, stream>>>(contains_dst, cnt);
  scan_blocks<<<(NNODE + 1023) / 1024, 256, 0, stream>>>(cnt, pre, bsum, NNODE);
  scan_partials<<<1, 128, 0, stream>>>(bsum, (NNODE + 1023) / 1024);
  finalize_rowptr<<<(NNODE + 255) / 256, 256, 0, stream>>>(pre, bsum, rowptr_n, NNODE);
  scatter_csr<<<EB, 256, 0, stream>>>(contains_src, contains_dst, rowptr_n, cursor, csr_n);

  // ---- layers ----
  for (int l = 0; l < NLAY; ++l) {
    // n2c: src=xn (NNODE), dst=xc (NCLS)
    gemm128<<<(NNODE + 63) / 64, 256, 0, stream>>>(xn, n2c_wl + l * HID * HID, n2c_bl + l * HID, xl, NNODE);
    gemm128<<<(NCLS + 63) / 64, 256, 0, stream>>>(xc, n2c_wr + l * HID * HID, n2c_br + l * HID, xr, NCLS);
    gat_dst<<<GAT_BLOCKS, 256, 0, stream>>>(xc, xl, xr, rowptr_c, csr_c,
                                            n2c_att + l * HID, n2c_bias + l * HID,
                                            ln_cg + l * HID, ln_cb + l * HID, NCLS);

    // c2n: src=xc (NCLS), dst=xn (NNODE)
    gemm128<<<(NCLS + 63) / 64, 256, 0, stream>>>(xc, c2n_wl + l * HID * HID, c2n_bl + l * HID, xl, NCLS);
    gemm128<<<(NNODE + 63) / 64, 256, 0, stream>>>(xn, c2n_wr + l * HID * HID, c2n_br + l * HID, xr, NNODE);
    gat_dst<<<GAT_BLOCKS, 256, 0, stream>>>(xn, xl, xr, rowptr_n, csr_n,
                                            c2n_att + l * HID, c2n_bias + l * HID,
                                            ln_ng + l * HID, ln_nb + l * HID, NNODE);
  }

  hipMemsetAsync(acc, 0, HID * sizeof(float), stream);
  colsum<<<256, HID, 0, stream>>>(xc, acc);
  final_out<<<1, HID, 0, stream>>>(acc, (float*)d_out);
}

// Round 4
// 1670.214 us; speedup vs baseline: 1.1961x; 1.1961x over previous
//
#include <hip/hip_runtime.h>

#define NNODE 100000
#define NCLS  50000
#define NEDGE 400000
#define NDIM  43
#define CDIM  2
#define HID   128
#define NHEAD 4
#define CHN   32
#define NLAY  4

// ---------------------------------------------------------------------------
// Generic small-K projection (used for class proj, K=2).
__global__ void proj_kernel(const float* __restrict__ X, const float* __restrict__ W,
                            const float* __restrict__ B, float* __restrict__ Y,
                            int nrows, int K) {
  int t = blockIdx.x * blockDim.x + threadIdx.x;
  if (t >= nrows * HID) return;
  int i = t >> 7, j = t & (HID - 1);
  float acc = B[j];
  for (int k = 0; k < K; ++k)
    acc = fmaf(X[i * K + k], W[k * HID + j], acc);
  Y[t] = acc;
}

// ---------------------------------------------------------------------------
// Node projection, K=43, LDS-tiled. 32 rows/block, 256 threads, 4x4 per thread.
__global__ __launch_bounds__(256) void proj_node(const float* __restrict__ X,
                                                 const float* __restrict__ W,
                                                 const float* __restrict__ B,
                                                 float* __restrict__ Y) {
  __shared__ float Ws[NDIM][HID];   // 22016 B, [k][j]
  __shared__ float Xs[32][NDIM];    // 5504 B,  [r][k]
  const int tid = threadIdx.x;
  const int row0 = blockIdx.x * 32;

  for (int i = tid; i < NDIM * (HID / 4); i += 256) {
    int k = i >> 5, j4 = (i & 31) << 2;
    *(float4*)&Ws[k][j4] = *(const float4*)&W[(size_t)k * HID + j4];
  }
  const float* Xb = X + (size_t)row0 * NDIM;
  for (int i = tid; i < 32 * NDIM; i += 256) ((float*)Xs)[i] = Xb[i];
  __syncthreads();

  const int cg = tid & 31, rg = tid >> 5;
  const int j0 = cg * 4, r0 = rg * 4;

  float acc[4][4];
#pragma unroll
  for (int rr = 0; rr < 4; ++rr)
#pragma unroll
    for (int cc = 0; cc < 4; ++cc) acc[rr][cc] = 0.f;

#pragma unroll 4
  for (int k = 0; k < NDIM; ++k) {
    const float4 w = *(const float4*)&Ws[k][j0];
    const float wv[4] = {w.x, w.y, w.z, w.w};
    const float xx[4] = {Xs[r0 + 0][k], Xs[r0 + 1][k], Xs[r0 + 2][k], Xs[r0 + 3][k]};
#pragma unroll
    for (int rr = 0; rr < 4; ++rr)
#pragma unroll
      for (int cc = 0; cc < 4; ++cc)
        acc[rr][cc] = fmaf(xx[rr], wv[cc], acc[rr][cc]);
  }

  const float4 bv = *(const float4*)&B[j0];
  const float bb[4] = {bv.x, bv.y, bv.z, bv.w};
#pragma unroll
  for (int rr = 0; rr < 4; ++rr) {
    float4 o = make_float4(acc[rr][0] + bb[0], acc[rr][1] + bb[1],
                           acc[rr][2] + bb[2], acc[rr][3] + bb[3]);
    *(float4*)&Y[(size_t)(row0 + r0 + rr) * HID + j0] = o;
  }
}

// ---------------------------------------------------------------------------
// Y[r][j] = B[j] + sum_k X[r][k]*W[k][j],  X f32 [nrows][128], W f32 [128][128].
// v4 = R2 structure + register-staged prefetch pipeline (T14):
//  - wave owns 16 rows (uniform), lanes span 128 cols (j0 = lane*2)
//  - W read: 1 conflict-free ds_read_b64 per k; X: 4 broadcast ds_read_b128
//  - kc+1's W/X global loads are ISSUED right after compute on kc starts;
//    the vmcnt wait lands at the next ds_write, after ~3K cycles of compute,
//    removing the per-kc staging drain stall.
__global__ __launch_bounds__(256) void gemm128(const float* __restrict__ X,
                                               const float* __restrict__ W,
                                               const float* __restrict__ B,
                                               float* __restrict__ Y, int nrows) {
  __shared__ float Ws[32][HID];   // 16 KB, [k][j]
  __shared__ float XsT[32][64];   // 8 KB,  [k][r]
  const int tid = threadIdx.x;
  const int row0 = blockIdx.x * 64;
  const int lane = tid & 63;
  const int rg = tid >> 6;        // wave id -> row group
  const int r0 = rg * 16;
  const int j0 = lane * 2;

  float acc[16][2];
#pragma unroll
  for (int rr = 0; rr < 16; ++rr) { acc[rr][0] = 0.f; acc[rr][1] = 0.f; }

  float4 wreg[4], xreg[2];
  // prologue: load chunk kc=0 into registers
#pragma unroll
  for (int q = 0; q < 4; ++q) {
    int i = tid + q * 256;
    int k = i >> 5, j4 = (i & 31) << 2;
    wreg[q] = *(const float4*)&W[(size_t)k * HID + j4];
  }
#pragma unroll
  for (int q = 0; q < 2; ++q) {
    int i = tid + q * 256;
    int r = i >> 3, kq = (i & 7) << 2;
    int gr = row0 + r;
    xreg[q] = (gr < nrows) ? *(const float4*)&X[(size_t)gr * HID + kq]
                           : make_float4(0.f, 0.f, 0.f, 0.f);
  }

  for (int kc = 0; kc < 4; ++kc) {
    // write current registers to LDS (vmcnt for these loads drains here,
    // ~a full compute phase after issue)
#pragma unroll
    for (int q = 0; q < 4; ++q) {
      int i = tid + q * 256;
      int k = i >> 5, j4 = (i & 31) << 2;
      *(float4*)&Ws[k][j4] = wreg[q];
    }
#pragma unroll
    for (int q = 0; q < 2; ++q) {
      int i = tid + q * 256;
      int r = i >> 3, kq = (i & 7) << 2;
      float4 v = xreg[q];
      XsT[kq + 0][r] = v.x;
      XsT[kq + 1][r] = v.y;
      XsT[kq + 2][r] = v.z;
      XsT[kq + 3][r] = v.w;
    }
    __syncthreads();

    // issue next chunk's global loads (latency hides under compute below)
    if (kc < 3) {
      const int k0n = (kc + 1) * 32;
#pragma unroll
      for (int q = 0; q < 4; ++q) {
        int i = tid + q * 256;
        int k = i >> 5, j4 = (i & 31) << 2;
        wreg[q] = *(const float4*)&W[(size_t)(k0n + k) * HID + j4];
      }
#pragma unroll
      for (int q = 0; q < 2; ++q) {
        int i = tid + q * 256;
        int r = i >> 3, kq = (i & 7) << 2;
        int gr = row0 + r;
        xreg[q] = (gr < nrows) ? *(const float4*)&X[(size_t)gr * HID + k0n + kq]
                               : make_float4(0.f, 0.f, 0.f, 0.f);
      }
    }

#pragma unroll 4
    for (int k = 0; k < 32; ++k) {
      const float2 w = *(const float2*)&Ws[k][j0];
      const float4 xa = *(const float4*)&XsT[k][r0];
      const float4 xb = *(const float4*)&XsT[k][r0 + 4];
      const float4 xc4 = *(const float4*)&XsT[k][r0 + 8];
      const float4 xd = *(const float4*)&XsT[k][r0 + 12];
      const float xx[16] = {xa.x, xa.y, xa.z, xa.w, xb.x, xb.y, xb.z, xb.w,
                            xc4.x, xc4.y, xc4.z, xc4.w, xd.x, xd.y, xd.z, xd.w};
#pragma unroll
      for (int rr = 0; rr < 16; ++rr) {
        acc[rr][0] = fmaf(xx[rr], w.x, acc[rr][0]);
        acc[rr][1] = fmaf(xx[rr], w.y, acc[rr][1]);
      }
    }
    __syncthreads();
  }

  const float2 bv = *(const float2*)&B[j0];
#pragma unroll
  for (int rr = 0; rr < 16; ++rr) {
    int gr = row0 + r0 + rr;
    if (gr < nrows) {
      float2 o = make_float2(acc[rr][0] + bv.x, acc[rr][1] + bv.y);
      *(float2*)&Y[(size_t)gr * HID + j0] = o;
    }
  }
}

// ---------------------------------------------------------------------------
// CSR build: histogram -> scan -> scatter
__global__ void hist_kernel(const int* __restrict__ dst, int* __restrict__ cnt) {
  int e = blockIdx.x * 256 + threadIdx.x;
  if (e < NEDGE) atomicAdd(&cnt[dst[e]], 1);
}

__global__ __launch_bounds__(256) void scan_blocks(const int* __restrict__ cnt,
                                                   int* __restrict__ pre,
                                                   int* __restrict__ bsum, int n) {
  __shared__ int sdata[256];
  const int b = blockIdx.x, t = threadIdx.x;
  const int base = b * 1024 + t * 4;
  int v[4], s = 0;
#pragma unroll
  for (int q = 0; q < 4; ++q) {
    int i = base + q;
    v[q] = (i < n) ? cnt[i] : 0;
    s += v[q];
  }
  sdata[t] = s;
  __syncthreads();
  for (int off = 1; off < 256; off <<= 1) {
    int y = (t >= off) ? sdata[t - off] : 0;
    __syncthreads();
    sdata[t] += y;
    __syncthreads();
  }
  int run = sdata[t] - s;  // exclusive prefix of thread sums
  if (t == 255) bsum[b] = sdata[255];
#pragma unroll
  for (int q = 0; q < 4; ++q) {
    int i = base + q;
    if (i < n) pre[i] = run;
    run += v[q];
  }
}

// single block; nb <= 128
__global__ __launch_bounds__(128) void scan_partials(int* __restrict__ bsum, int nb) {
  __shared__ int sd[128];
  int t = threadIdx.x;
  int v = (t < nb) ? bsum[t] : 0;
  sd[t] = v;
  __syncthreads();
  for (int off = 1; off < 128; off <<= 1) {
    int y = (t >= off) ? sd[t - off] : 0;
    __syncthreads();
    sd[t] += y;
    __syncthreads();
  }
  if (t < nb) bsum[t] = sd[t] - v;  // exclusive
}

__global__ void finalize_rowptr(const int* __restrict__ pre, const int* __restrict__ bsum,
                                int* __restrict__ rowptr, int n) {
  int i = blockIdx.x * 256 + threadIdx.x;
  if (i < n) rowptr[i] = pre[i] + bsum[i >> 10];
  if (i == 0) rowptr[n] = NEDGE;
}

__global__ void scatter_csr(const int* __restrict__ src, const int* __restrict__ dst,
                            const int* __restrict__ rowptr, int* __restrict__ cursor,
                            int* __restrict__ csr_src) {
  int e = blockIdx.x * 256 + threadIdx.x;
  if (e >= NEDGE) return;
  int d = dst[e];
  int p = atomicAdd(&cursor[d], 1);
  csr_src[rowptr[d] + p] = src[e];
}

// ---------------------------------------------------------------------------
// Fused per-dst GATv2: persistent, one wave (64 lanes x float2) per dst row.
__global__ __launch_bounds__(256) void gat_dst(float* __restrict__ x,          // [n_dst][128] inout
                                               const float* __restrict__ xl,   // [n_src][128]
                                               const float* __restrict__ xr,   // [n_dst][128]
                                               const int* __restrict__ rowptr,
                                               const int* __restrict__ csr_src,
                                               const float* __restrict__ att,  // [128]
                                               const float* __restrict__ bias,
                                               const float* __restrict__ g,
                                               const float* __restrict__ b,
                                               int n_dst) {
  const int wave = threadIdx.x >> 6;     // 0..3
  const int lane = threadIdx.x & 63;
  const int j = lane * 2;                // channels j, j+1; head = j>>5 = lane>>4

  const float2 attv = *(const float2*)&att[j];
  const float2 bias2 = *(const float2*)&bias[j];
  const float2 g2 = *(const float2*)&g[j];
  const float2 b2 = *(const float2*)&b[j];

  const int stride = gridDim.x * 4;
  for (int d = blockIdx.x * 4 + wave; d < n_dst; d += stride) {
    const float2 xrv = *(const float2*)&xr[(size_t)d * HID + j];
    const int e0 = rowptr[d], e1 = rowptr[d + 1];

    float2 acc = make_float2(0.f, 0.f);
    float den = 0.f;
    int idx = e0;
    for (; idx + 1 < e1; idx += 2) {
      const int s0 = csr_src[idx];
      const int s1 = csr_src[idx + 1];
      const float2 v0 = *(const float2*)&xl[(size_t)s0 * HID + j];
      const float2 v1 = *(const float2*)&xl[(size_t)s1 * HID + j];
      {
        float m0 = v0.x + xrv.x; m0 = m0 > 0.f ? m0 : 0.2f * m0;
        float m1 = v0.y + xrv.y; m1 = m1 > 0.f ? m1 : 0.2f * m1;
        float p = fmaf(attv.x, m0, attv.y * m1);
        p += __shfl_xor(p, 8); p += __shfl_xor(p, 4);
        p += __shfl_xor(p, 2); p += __shfl_xor(p, 1);
        float e_ = __expf(p);
        acc.x = fmaf(e_, v0.x, acc.x);
        acc.y = fmaf(e_, v0.y, acc.y);
        den += e_;
      }
      {
        float m0 = v1.x + xrv.x; m0 = m0 > 0.f ? m0 : 0.2f * m0;
        float m1 = v1.y + xrv.y; m1 = m1 > 0.f ? m1 : 0.2f * m1;
        float p = fmaf(attv.x, m0, attv.y * m1);
        p += __shfl_xor(p, 8); p += __shfl_xor(p, 4);
        p += __shfl_xor(p, 2); p += __shfl_xor(p, 1);
        float e_ = __expf(p);
        acc.x = fmaf(e_, v1.x, acc.x);
        acc.y = fmaf(e_, v1.y, acc.y);
        den += e_;
      }
    }
    if (idx < e1) {
      const int s0 = csr_src[idx];
      const float2 v0 = *(const float2*)&xl[(size_t)s0 * HID + j];
      float m0 = v0.x + xrv.x; m0 = m0 > 0.f ? m0 : 0.2f * m0;
      float m1 = v0.y + xrv.y; m1 = m1 > 0.f ? m1 : 0.2f * m1;
      float p = fmaf(attv.x, m0, attv.y * m1);
      p += __shfl_xor(p, 8); p += __shfl_xor(p, 4);
      p += __shfl_xor(p, 2); p += __shfl_xor(p, 1);
      float e_ = __expf(p);
      acc.x = fmaf(e_, v0.x, acc.x);
      acc.y = fmaf(e_, v0.y, acc.y);
      den += e_;
    }

    float2 outv = make_float2(0.f, 0.f);
    if (e1 > e0) { outv.x = acc.x / den; outv.y = acc.y / den; }

    const float2 xv = *(const float2*)&x[(size_t)d * HID + j];
    float vx = xv.x + outv.x + bias2.x;
    float vy = xv.y + outv.y + bias2.y;

    // LayerNorm across the wave (64 lanes x 2 channels = 128)
    float s1 = vx + vy;
    float s2 = vx * vx + vy * vy;
#pragma unroll
    for (int off = 32; off > 0; off >>= 1) {
      s1 += __shfl_xor(s1, off);
      s2 += __shfl_xor(s2, off);
    }
    const float mu = s1 * (1.0f / HID);
    const float var = s2 * (1.0f / HID) - mu * mu;
    const float inv = rsqrtf(var + 1e-5f);
    float2 o = make_float2((vx - mu) * inv * g2.x + b2.x,
                           (vy - mu) * inv * g2.y + b2.y);
    *(float2*)&x[(size_t)d * HID + j] = o;
  }
}

// ---------------------------------------------------------------------------
__global__ void colsum(const float* __restrict__ xc, float* __restrict__ acc) {
  int j = threadIdx.x;  // 128 threads
  int per = (NCLS + gridDim.x - 1) / gridDim.x;
  int r0 = blockIdx.x * per;
  int r1 = min(r0 + per, NCLS);
  float s = 0.f;
  for (int r = r0; r < r1; ++r) s += xc[(size_t)r * HID + j];
  atomicAdd(&acc[j], s);
}

__global__ void final_out(const float* __restrict__ acc, float* __restrict__ out) {
  int j = threadIdx.x;
  out[j] = acc[j] * (1.0f / NCLS);
}

// ---------------------------------------------------------------------------
extern "C" void kernel_launch(void* const* d_in, const int* in_sizes, int n_in,
                              void* d_out, int out_size, void* d_ws, size_t ws_size,
                              hipStream_t stream) {
  (void)in_sizes; (void)n_in; (void)out_size; (void)ws_size;
  const float* x_node     = (const float*)d_in[0];
  const float* x_class    = (const float*)d_in[1];
  const int* member_src   = (const int*)d_in[2];
  const int* member_dst   = (const int*)d_in[3];
  const int* contains_src = (const int*)d_in[4];
  const int* contains_dst = (const int*)d_in[5];
  const float* npw = (const float*)d_in[6];
  const float* npb = (const float*)d_in[7];
  const float* cpw = (const float*)d_in[8];
  const float* cpb = (const float*)d_in[9];
  const float* n2c_wl   = (const float*)d_in[10];
  const float* n2c_bl   = (const float*)d_in[11];
  const float* n2c_wr   = (const float*)d_in[12];
  const float* n2c_br   = (const float*)d_in[13];
  const float* n2c_att  = (const float*)d_in[14];
  const float* n2c_bias = (const float*)d_in[15];
  const float* c2n_wl   = (const float*)d_in[16];
  const float* c2n_bl   = (const float*)d_in[17];
  const float* c2n_wr   = (const float*)d_in[18];
  const float* c2n_br   = (const float*)d_in[19];
  const float* c2n_att  = (const float*)d_in[20];
  const float* c2n_bias = (const float*)d_in[21];
  const float* ln_cg = (const float*)d_in[22];
  const float* ln_cb = (const float*)d_in[23];
  const float* ln_ng = (const float*)d_in[24];
  const float* ln_nb = (const float*)d_in[25];

  float* ws  = (float*)d_ws;
  float* xn  = ws;                                  // NNODE*128
  float* xc  = xn  + (size_t)NNODE * HID;           // NCLS*128
  float* xl  = xc  + (size_t)NCLS * HID;            // NNODE*128
  float* xr  = xl  + (size_t)NNODE * HID;           // NNODE*128
  float* acc = xr  + (size_t)NNODE * HID;           // 128
  int* ip        = (int*)(acc + 128);
  int* rowptr_c  = ip;                              // NCLS+1
  int* csr_c     = rowptr_c + (NCLS + 1);           // NEDGE
  int* rowptr_n  = csr_c + NEDGE;                   // NNODE+1
  int* csr_n     = rowptr_n + (NNODE + 1);          // NEDGE
  int* cnt       = csr_n + NEDGE;                   // NNODE (max)
  int* cursor    = cnt + NNODE;                     // NNODE
  int* pre       = cursor + NNODE;                  // NNODE
  int* bsum      = pre + NNODE;                     // 128

  const int EB = (NEDGE + 255) / 256;
  const int GAT_BLOCKS = 2048;  // persistent: 2048 blocks x 4 waves

  // ---- initial projections ----
  proj_node<<<NNODE / 32, 256, 0, stream>>>(x_node, npw, npb, xn);
  proj_kernel<<<(NCLS * HID + 255) / 256, 256, 0, stream>>>(x_class, cpw, cpb, xc, NCLS, CDIM);

  // ---- CSR build: member (dst=class) ----
  hipMemsetAsync(cnt, 0, NCLS * sizeof(int), stream);
  hipMemsetAsync(cursor, 0, NCLS * sizeof(int), stream);
  hist_kernel<<<EB, 256, 0, stream>>>(member_dst, cnt);
  scan_blocks<<<(NCLS + 1023) / 1024, 256, 0, stream>>>(cnt, pre, bsum, NCLS);
  scan_partials<<<1, 128, 0, stream>>>(bsum, (NCLS + 1023) / 1024);
  finalize_rowptr<<<(NCLS + 255) / 256, 256, 0, stream>>>(pre, bsum, rowptr_c, NCLS);
  scatter_csr<<<EB, 256, 0, stream>>>(member_src, member_dst, rowptr_c, cursor, csr_c);

  // ---- CSR build: contains (dst=node) ----
  hipMemsetAsync(cnt, 0, NNODE * sizeof(int), stream);
  hipMemsetAsync(cursor, 0, NNODE * sizeof(int), stream);
  hist_kernel<<<EB, 256, 0, stream>>>(contains_dst, cnt);
  scan_blocks<<<(NNODE + 1023) / 1024, 256, 0, stream>>>(cnt, pre, bsum, NNODE);
  scan_partials<<<1, 128, 0, stream>>>(bsum, (NNODE + 1023) / 1024);
  finalize_rowptr<<<(NNODE + 255) / 256, 256, 0, stream>>>(pre, bsum, rowptr_n, NNODE);
  scatter_csr<<<EB, 256, 0, stream>>>(contains_src, contains_dst, rowptr_n, cursor, csr_n);

  // ---- layers ----
  for (int l = 0; l < NLAY; ++l) {
    // n2c: src=xn (NNODE), dst=xc (NCLS)
    gemm128<<<(NNODE + 63) / 64, 256, 0, stream>>>(xn, n2c_wl + l * HID * HID, n2c_bl + l * HID, xl, NNODE);
    gemm128<<<(NCLS + 63) / 64, 256, 0, stream>>>(xc, n2c_wr + l * HID * HID, n2c_br + l * HID, xr, NCLS);
    gat_dst<<<GAT_BLOCKS, 256, 0, stream>>>(xc, xl, xr, rowptr_c, csr_c,
                                            n2c_att + l * HID, n2c_bias + l * HID,
                                            ln_cg + l * HID, ln_cb + l * HID, NCLS);

    // c2n: src=xc (NCLS), dst=xn (NNODE)
    gemm128<<<(NCLS + 63) / 64, 256, 0, stream>>>(xc, c2n_wl + l * HID * HID, c2n_bl + l * HID, xl, NCLS);
    gemm128<<<(NNODE + 63) / 64, 256, 0, stream>>>(xn, c2n_wr + l * HID * HID, c2n_br + l * HID, xr, NNODE);
    gat_dst<<<GAT_BLOCKS, 256, 0, stream>>>(xn, xl, xr, rowptr_n, csr_n,
                                            c2n_att + l * HID, c2n_bias + l * HID,
                                            ln_ng + l * HID, ln_nb + l * HID, NNODE);
  }

  hipMemsetAsync(acc, 0, HID * sizeof(float), stream);
  colsum<<<256, HID, 0, stream>>>(xc, acc);
  final_out<<<1, HID, 0, stream>>>(acc, (float*)d_out);
}

// Round 5
// 1649.384 us; speedup vs baseline: 1.2112x; 1.0126x over previous
//
#include <hip/hip_runtime.h>

#define NNODE 100000
#define NCLS  50000
#define NEDGE 400000
#define NDIM  43
#define CDIM  2
#define HID   128
#define NHEAD 4
#define CHN   32
#define NLAY  4

// ---------------------------------------------------------------------------
// Generic small-K projection (used for class proj, K=2).
__global__ void proj_kernel(const float* __restrict__ X, const float* __restrict__ W,
                            const float* __restrict__ B, float* __restrict__ Y,
                            int nrows, int K) {
  int t = blockIdx.x * blockDim.x + threadIdx.x;
  if (t >= nrows * HID) return;
  int i = t >> 7, j = t & (HID - 1);
  float acc = B[j];
  for (int k = 0; k < K; ++k)
    acc = fmaf(X[i * K + k], W[k * HID + j], acc);
  Y[t] = acc;
}

// ---------------------------------------------------------------------------
// Node projection, K=43, LDS-tiled. 32 rows/block, 256 threads, 4x4 per thread.
__global__ __launch_bounds__(256) void proj_node(const float* __restrict__ X,
                                                 const float* __restrict__ W,
                                                 const float* __restrict__ B,
                                                 float* __restrict__ Y) {
  __shared__ float Ws[NDIM][HID];   // 22016 B, [k][j]
  __shared__ float Xs[32][NDIM];    // 5504 B,  [r][k]
  const int tid = threadIdx.x;
  const int row0 = blockIdx.x * 32;

  for (int i = tid; i < NDIM * (HID / 4); i += 256) {
    int k = i >> 5, j4 = (i & 31) << 2;
    *(float4*)&Ws[k][j4] = *(const float4*)&W[(size_t)k * HID + j4];
  }
  const float* Xb = X + (size_t)row0 * NDIM;
  for (int i = tid; i < 32 * NDIM; i += 256) ((float*)Xs)[i] = Xb[i];
  __syncthreads();

  const int cg = tid & 31, rg = tid >> 5;
  const int j0 = cg * 4, r0 = rg * 4;

  float acc[4][4];
#pragma unroll
  for (int rr = 0; rr < 4; ++rr)
#pragma unroll
    for (int cc = 0; cc < 4; ++cc) acc[rr][cc] = 0.f;

#pragma unroll 4
  for (int k = 0; k < NDIM; ++k) {
    const float4 w = *(const float4*)&Ws[k][j0];
    const float wv[4] = {w.x, w.y, w.z, w.w};
    const float xx[4] = {Xs[r0 + 0][k], Xs[r0 + 1][k], Xs[r0 + 2][k], Xs[r0 + 3][k]};
#pragma unroll
    for (int rr = 0; rr < 4; ++rr)
#pragma unroll
      for (int cc = 0; cc < 4; ++cc)
        acc[rr][cc] = fmaf(xx[rr], wv[cc], acc[rr][cc]);
  }

  const float4 bv = *(const float4*)&B[j0];
  const float bb[4] = {bv.x, bv.y, bv.z, bv.w};
#pragma unroll
  for (int rr = 0; rr < 4; ++rr) {
    float4 o = make_float4(acc[rr][0] + bb[0], acc[rr][1] + bb[1],
                           acc[rr][2] + bb[2], acc[rr][3] + bb[3]);
    *(float4*)&Y[(size_t)(row0 + r0 + rr) * HID + j0] = o;
  }
}

// ---------------------------------------------------------------------------
// Y[r][j] = B[j] + sum_k X[r][k]*W[k][j],  X f32 [nrows][128], W f32 [128][128].
// v5: X never touches LDS.
//  - wave owns 16 rows; lanes span all 128 cols (j0 = lane*2)
//  - X chunk (16 rows x 32 k = 8 VGPR/lane) lives in registers, loaded
//    coalesced and prefetched one chunk ahead; per-(r,k) value delivered
//    wave-uniform via v_readlane (VALU, no LDS, no latency)
//  - W staged ONCE in 64 KB LDS; per wave-k a single conflict-free
//    ds_read_b64 -> LDS pipe ~24 cyc/block-k vs 96 cyc VALU: unbound
//  - no inner barriers at all (one barrier after W staging)
__global__ __launch_bounds__(256) void gemm128(const float* __restrict__ X,
                                               const float* __restrict__ W,
                                               const float* __restrict__ B,
                                               float* __restrict__ Y, int nrows) {
  __shared__ float Ws[HID][HID];  // 64 KB
  const int tid = threadIdx.x;
  const int row0 = blockIdx.x * 64;
  const int lane = tid & 63;
  const int wv = tid >> 6;        // wave id -> row group
  const int r0 = wv * 16;
  const int j0 = lane * 2;

  // per-lane X source rows for the register chunks:
  // reg q (0..7) holds X[row0+r0+2q+(lane>>5)][k0 + (lane&31)]
  const int xrow = row0 + r0 + (lane >> 5);   // + 2q added per reg
  const int xcol = lane & 31;                 // + k0 per chunk

  // issue chunk kc=0 X loads first (latency hides under W staging)
  float xv[8];
#pragma unroll
  for (int q = 0; q < 8; ++q) {
    int gr = xrow + 2 * q;
    gr = gr < nrows ? gr : nrows - 1;
    xv[q] = X[(size_t)gr * HID + xcol];
  }

  // stage all of W: 4096 float4, 16 per thread, coalesced
  for (int i = tid; i < 4096; i += 256) {
    int k = i >> 5, j4 = (i & 31) << 2;
    *(float4*)&Ws[k][j4] = *(const float4*)&W[(size_t)k * HID + j4];
  }
  __syncthreads();

  float acc[16][2];
#pragma unroll
  for (int rr = 0; rr < 16; ++rr) { acc[rr][0] = 0.f; acc[rr][1] = 0.f; }

  for (int kc = 0; kc < 4; ++kc) {
    // prefetch next chunk's X into registers (drains after this kc's compute)
    float xn_[8];
    if (kc < 3) {
      const int k0n = (kc + 1) * 32;
#pragma unroll
      for (int q = 0; q < 8; ++q) {
        int gr = xrow + 2 * q;
        gr = gr < nrows ? gr : nrows - 1;
        xn_[q] = X[(size_t)gr * HID + k0n + xcol];
      }
    }

    const int kb = kc * 32;
#pragma unroll
    for (int k = 0; k < 32; ++k) {
      const float2 w = *(const float2*)&Ws[kb + k][j0];  // ds_read_b64, conflict-free
#pragma unroll
      for (int r = 0; r < 16; ++r) {
        // X[r0+r][kb+k] lives in lane ((r&1)<<5)+k, reg r>>1 (wave-uniform)
        float xs = __uint_as_float(
            __builtin_amdgcn_readlane(__float_as_uint(xv[r >> 1]), ((r & 1) << 5) + k));
        acc[r][0] = fmaf(xs, w.x, acc[r][0]);
        acc[r][1] = fmaf(xs, w.y, acc[r][1]);
      }
    }

    if (kc < 3) {
#pragma unroll
      for (int q = 0; q < 8; ++q) xv[q] = xn_[q];
    }
  }

  const float2 bv = *(const float2*)&B[j0];
#pragma unroll
  for (int rr = 0; rr < 16; ++rr) {
    int gr = row0 + r0 + rr;
    if (gr < nrows) {
      float2 o = make_float2(acc[rr][0] + bv.x, acc[rr][1] + bv.y);
      *(float2*)&Y[(size_t)gr * HID + j0] = o;
    }
  }
}

// ---------------------------------------------------------------------------
// CSR build: histogram -> scan -> scatter
__global__ void hist_kernel(const int* __restrict__ dst, int* __restrict__ cnt) {
  int e = blockIdx.x * 256 + threadIdx.x;
  if (e < NEDGE) atomicAdd(&cnt[dst[e]], 1);
}

__global__ __launch_bounds__(256) void scan_blocks(const int* __restrict__ cnt,
                                                   int* __restrict__ pre,
                                                   int* __restrict__ bsum, int n) {
  __shared__ int sdata[256];
  const int b = blockIdx.x, t = threadIdx.x;
  const int base = b * 1024 + t * 4;
  int v[4], s = 0;
#pragma unroll
  for (int q = 0; q < 4; ++q) {
    int i = base + q;
    v[q] = (i < n) ? cnt[i] : 0;
    s += v[q];
  }
  sdata[t] = s;
  __syncthreads();
  for (int off = 1; off < 256; off <<= 1) {
    int y = (t >= off) ? sdata[t - off] : 0;
    __syncthreads();
    sdata[t] += y;
    __syncthreads();
  }
  int run = sdata[t] - s;  // exclusive prefix of thread sums
  if (t == 255) bsum[b] = sdata[255];
#pragma unroll
  for (int q = 0; q < 4; ++q) {
    int i = base + q;
    if (i < n) pre[i] = run;
    run += v[q];
  }
}

// single block; nb <= 128
__global__ __launch_bounds__(128) void scan_partials(int* __restrict__ bsum, int nb) {
  __shared__ int sd[128];
  int t = threadIdx.x;
  int v = (t < nb) ? bsum[t] : 0;
  sd[t] = v;
  __syncthreads();
  for (int off = 1; off < 128; off <<= 1) {
    int y = (t >= off) ? sd[t - off] : 0;
    __syncthreads();
    sd[t] += y;
    __syncthreads();
  }
  if (t < nb) bsum[t] = sd[t] - v;  // exclusive
}

__global__ void finalize_rowptr(const int* __restrict__ pre, const int* __restrict__ bsum,
                                int* __restrict__ rowptr, int n) {
  int i = blockIdx.x * 256 + threadIdx.x;
  if (i < n) rowptr[i] = pre[i] + bsum[i >> 10];
  if (i == 0) rowptr[n] = NEDGE;
}

__global__ void scatter_csr(const int* __restrict__ src, const int* __restrict__ dst,
                            const int* __restrict__ rowptr, int* __restrict__ cursor,
                            int* __restrict__ csr_src) {
  int e = blockIdx.x * 256 + threadIdx.x;
  if (e >= NEDGE) return;
  int d = dst[e];
  int p = atomicAdd(&cursor[d], 1);
  csr_src[rowptr[d] + p] = src[e];
}

// ---------------------------------------------------------------------------
// Fused per-dst GATv2: persistent, one wave (64 lanes x float2) per dst row.
__global__ __launch_bounds__(256) void gat_dst(float* __restrict__ x,          // [n_dst][128] inout
                                               const float* __restrict__ xl,   // [n_src][128]
                                               const float* __restrict__ xr,   // [n_dst][128]
                                               const int* __restrict__ rowptr,
                                               const int* __restrict__ csr_src,
                                               const float* __restrict__ att,  // [128]
                                               const float* __restrict__ bias,
                                               const float* __restrict__ g,
                                               const float* __restrict__ b,
                                               int n_dst) {
  const int wave = threadIdx.x >> 6;     // 0..3
  const int lane = threadIdx.x & 63;
  const int j = lane * 2;                // channels j, j+1; head = j>>5 = lane>>4

  const float2 attv = *(const float2*)&att[j];
  const float2 bias2 = *(const float2*)&bias[j];
  const float2 g2 = *(const float2*)&g[j];
  const float2 b2 = *(const float2*)&b[j];

  const int stride = gridDim.x * 4;
  for (int d = blockIdx.x * 4 + wave; d < n_dst; d += stride) {
    const float2 xrv = *(const float2*)&xr[(size_t)d * HID + j];
    const int e0 = rowptr[d], e1 = rowptr[d + 1];

    float2 acc = make_float2(0.f, 0.f);
    float den = 0.f;
    int idx = e0;
    for (; idx + 1 < e1; idx += 2) {
      const int s0 = csr_src[idx];
      const int s1 = csr_src[idx + 1];
      const float2 v0 = *(const float2*)&xl[(size_t)s0 * HID + j];
      const float2 v1 = *(const float2*)&xl[(size_t)s1 * HID + j];
      {
        float m0 = v0.x + xrv.x; m0 = m0 > 0.f ? m0 : 0.2f * m0;
        float m1 = v0.y + xrv.y; m1 = m1 > 0.f ? m1 : 0.2f * m1;
        float p = fmaf(attv.x, m0, attv.y * m1);
        p += __shfl_xor(p, 8); p += __shfl_xor(p, 4);
        p += __shfl_xor(p, 2); p += __shfl_xor(p, 1);
        float e_ = __expf(p);
        acc.x = fmaf(e_, v0.x, acc.x);
        acc.y = fmaf(e_, v0.y, acc.y);
        den += e_;
      }
      {
        float m0 = v1.x + xrv.x; m0 = m0 > 0.f ? m0 : 0.2f * m0;
        float m1 = v1.y + xrv.y; m1 = m1 > 0.f ? m1 : 0.2f * m1;
        float p = fmaf(attv.x, m0, attv.y * m1);
        p += __shfl_xor(p, 8); p += __shfl_xor(p, 4);
        p += __shfl_xor(p, 2); p += __shfl_xor(p, 1);
        float e_ = __expf(p);
        acc.x = fmaf(e_, v1.x, acc.x);
        acc.y = fmaf(e_, v1.y, acc.y);
        den += e_;
      }
    }
    if (idx < e1) {
      const int s0 = csr_src[idx];
      const float2 v0 = *(const float2*)&xl[(size_t)s0 * HID + j];
      float m0 = v0.x + xrv.x; m0 = m0 > 0.f ? m0 : 0.2f * m0;
      float m1 = v0.y + xrv.y; m1 = m1 > 0.f ? m1 : 0.2f * m1;
      float p = fmaf(attv.x, m0, attv.y * m1);
      p += __shfl_xor(p, 8); p += __shfl_xor(p, 4);
      p += __shfl_xor(p, 2); p += __shfl_xor(p, 1);
      float e_ = __expf(p);
      acc.x = fmaf(e_, v0.x, acc.x);
      acc.y = fmaf(e_, v0.y, acc.y);
      den += e_;
    }

    float2 outv = make_float2(0.f, 0.f);
    if (e1 > e0) { outv.x = acc.x / den; outv.y = acc.y / den; }

    const float2 xv = *(const float2*)&x[(size_t)d * HID + j];
    float vx = xv.x + outv.x + bias2.x;
    float vy = xv.y + outv.y + bias2.y;

    // LayerNorm across the wave (64 lanes x 2 channels = 128)
    float s1 = vx + vy;
    float s2 = vx * vx + vy * vy;
#pragma unroll
    for (int off = 32; off > 0; off >>= 1) {
      s1 += __shfl_xor(s1, off);
      s2 += __shfl_xor(s2, off);
    }
    const float mu = s1 * (1.0f / HID);
    const float var = s2 * (1.0f / HID) - mu * mu;
    const float inv = rsqrtf(var + 1e-5f);
    float2 o = make_float2((vx - mu) * inv * g2.x + b2.x,
                           (vy - mu) * inv * g2.y + b2.y);
    *(float2*)&x[(size_t)d * HID + j] = o;
  }
}

// ---------------------------------------------------------------------------
__global__ void colsum(const float* __restrict__ xc, float* __restrict__ acc) {
  int j = threadIdx.x;  // 128 threads
  int per = (NCLS + gridDim.x - 1) / gridDim.x;
  int r0 = blockIdx.x * per;
  int r1 = min(r0 + per, NCLS);
  float s = 0.f;
  for (int r = r0; r < r1; ++r) s += xc[(size_t)r * HID + j];
  atomicAdd(&acc[j], s);
}

__global__ void final_out(const float* __restrict__ acc, float* __restrict__ out) {
  int j = threadIdx.x;
  out[j] = acc[j] * (1.0f / NCLS);
}

// ---------------------------------------------------------------------------
extern "C" void kernel_launch(void* const* d_in, const int* in_sizes, int n_in,
                              void* d_out, int out_size, void* d_ws, size_t ws_size,
                              hipStream_t stream) {
  (void)in_sizes; (void)n_in; (void)out_size; (void)ws_size;
  const float* x_node     = (const float*)d_in[0];
  const float* x_class    = (const float*)d_in[1];
  const int* member_src   = (const int*)d_in[2];
  const int* member_dst   = (const int*)d_in[3];
  const int* contains_src = (const int*)d_in[4];
  const int* contains_dst = (const int*)d_in[5];
  const float* npw = (const float*)d_in[6];
  const float* npb = (const float*)d_in[7];
  const float* cpw = (const float*)d_in[8];
  const float* cpb = (const float*)d_in[9];
  const float* n2c_wl   = (const float*)d_in[10];
  const float* n2c_bl   = (const float*)d_in[11];
  const float* n2c_wr   = (const float*)d_in[12];
  const float* n2c_br   = (const float*)d_in[13];
  const float* n2c_att  = (const float*)d_in[14];
  const float* n2c_bias = (const float*)d_in[15];
  const float* c2n_wl   = (const float*)d_in[16];
  const float* c2n_bl   = (const float*)d_in[17];
  const float* c2n_wr   = (const float*)d_in[18];
  const float* c2n_br   = (const float*)d_in[19];
  const float* c2n_att  = (const float*)d_in[20];
  const float* c2n_bias = (const float*)d_in[21];
  const float* ln_cg = (const float*)d_in[22];
  const float* ln_cb = (const float*)d_in[23];
  const float* ln_ng = (const float*)d_in[24];
  const float* ln_nb = (const float*)d_in[25];

  float* ws  = (float*)d_ws;
  float* xn  = ws;                                  // NNODE*128
  float* xc  = xn  + (size_t)NNODE * HID;           // NCLS*128
  float* xl  = xc  + (size_t)NCLS * HID;            // NNODE*128
  float* xr  = xl  + (size_t)NNODE * HID;           // NNODE*128
  float* acc = xr  + (size_t)NNODE * HID;           // 128
  int* ip        = (int*)(acc + 128);
  int* rowptr_c  = ip;                              // NCLS+1
  int* csr_c     = rowptr_c + (NCLS + 1);           // NEDGE
  int* rowptr_n  = csr_c + NEDGE;                   // NNODE+1
  int* csr_n     = rowptr_n + (NNODE + 1);          // NEDGE
  int* cnt       = csr_n + NEDGE;                   // NNODE (max)
  int* cursor    = cnt + NNODE;                     // NNODE
  int* pre       = cursor + NNODE;                  // NNODE
  int* bsum      = pre + NNODE;                     // 128

  const int EB = (NEDGE + 255) / 256;
  const int GAT_BLOCKS = 2048;  // persistent: 2048 blocks x 4 waves

  // ---- initial projections ----
  proj_node<<<NNODE / 32, 256, 0, stream>>>(x_node, npw, npb, xn);
  proj_kernel<<<(NCLS * HID + 255) / 256, 256, 0, stream>>>(x_class, cpw, cpb, xc, NCLS, CDIM);

  // ---- CSR build: member (dst=class) ----
  hipMemsetAsync(cnt, 0, NCLS * sizeof(int), stream);
  hipMemsetAsync(cursor, 0, NCLS * sizeof(int), stream);
  hist_kernel<<<EB, 256, 0, stream>>>(member_dst, cnt);
  scan_blocks<<<(NCLS + 1023) / 1024, 256, 0, stream>>>(cnt, pre, bsum, NCLS);
  scan_partials<<<1, 128, 0, stream>>>(bsum, (NCLS + 1023) / 1024);
  finalize_rowptr<<<(NCLS + 255) / 256, 256, 0, stream>>>(pre, bsum, rowptr_c, NCLS);
  scatter_csr<<<EB, 256, 0, stream>>>(member_src, member_dst, rowptr_c, cursor, csr_c);

  // ---- CSR build: contains (dst=node) ----
  hipMemsetAsync(cnt, 0, NNODE * sizeof(int), stream);
  hipMemsetAsync(cursor, 0, NNODE * sizeof(int), stream);
  hist_kernel<<<EB, 256, 0, stream>>>(contains_dst, cnt);
  scan_blocks<<<(NNODE + 1023) / 1024, 256, 0, stream>>>(cnt, pre, bsum, NNODE);
  scan_partials<<<1, 128, 0, stream>>>(bsum, (NNODE + 1023) / 1024);
  finalize_rowptr<<<(NNODE + 255) / 256, 256, 0, stream>>>(pre, bsum, rowptr_n, NNODE);
  scatter_csr<<<EB, 256, 0, stream>>>(contains_src, contains_dst, rowptr_n, cursor, csr_n);

  // ---- layers ----
  for (int l = 0; l < NLAY; ++l) {
    // n2c: src=xn (NNODE), dst=xc (NCLS)
    gemm128<<<(NNODE + 63) / 64, 256, 0, stream>>>(xn, n2c_wl + l * HID * HID, n2c_bl + l * HID, xl, NNODE);
    gemm128<<<(NCLS + 63) / 64, 256, 0, stream>>>(xc, n2c_wr + l * HID * HID, n2c_br + l * HID, xr, NCLS);
    gat_dst<<<GAT_BLOCKS, 256, 0, stream>>>(xc, xl, xr, rowptr_c, csr_c,
                                            n2c_att + l * HID, n2c_bias + l * HID,
                                            ln_cg + l * HID, ln_cb + l * HID, NCLS);

    // c2n: src=xc (NCLS), dst=xn (NNODE)
    gemm128<<<(NCLS + 63) / 64, 256, 0, stream>>>(xc, c2n_wl + l * HID * HID, c2n_bl + l * HID, xl, NCLS);
    gemm128<<<(NNODE + 63) / 64, 256, 0, stream>>>(xn, c2n_wr + l * HID * HID, c2n_br + l * HID, xr, NNODE);
    gat_dst<<<GAT_BLOCKS, 256, 0, stream>>>(xn, xl, xr, rowptr_n, csr_n,
                                            c2n_att + l * HID, c2n_bias + l * HID,
                                            ln_ng + l * HID, ln_nb + l * HID, NNODE);
  }

  hipMemsetAsync(acc, 0, HID * sizeof(float), stream);
  colsum<<<256, HID, 0, stream>>>(xc, acc);
  final_out<<<1, HID, 0, stream>>>(acc, (float*)d_out);
}

// Round 6
// 1175.959 us; speedup vs baseline: 1.6988x; 1.4026x over previous
//
#include <hip/hip_runtime.h>

#define NNODE 100000
#define NCLS  50000
#define NEDGE 400000
#define NDIM  43
#define CDIM  2
#define HID   128
#define NHEAD 4
#define CHN   32
#define NLAY  4

typedef unsigned short u16;
typedef unsigned int u32;
typedef __attribute__((ext_vector_type(8))) short bf16x8;
typedef __attribute__((ext_vector_type(4))) float f32x4;

// fp32 -> bf16 round-to-nearest-even
__device__ __forceinline__ u16 f2bf(float f) {
  u32 u = __float_as_uint(f);
  return (u16)((u + 0x7FFFu + ((u >> 16) & 1u)) >> 16);
}
__device__ __forceinline__ float bf2f(u16 h) {
  return __uint_as_float(((u32)h) << 16);
}

// ---------------------------------------------------------------------------
// Class projection (K=2): writes hi/lo bf16 state arrays.
__global__ void proj_kernel(const float* __restrict__ X, const float* __restrict__ W,
                            const float* __restrict__ B, u16* __restrict__ Yh,
                            u16* __restrict__ Yl, int nrows, int K) {
  int t = blockIdx.x * blockDim.x + threadIdx.x;
  if (t >= nrows * HID) return;
  int i = t >> 7, j = t & (HID - 1);
  float acc = B[j];
  for (int k = 0; k < K; ++k)
    acc = fmaf(X[i * K + k], W[k * HID + j], acc);
  u16 h = f2bf(acc);
  Yh[t] = h;
  Yl[t] = f2bf(acc - bf2f(h));
}

// ---------------------------------------------------------------------------
// Node projection, K=43, LDS-tiled. Writes hi/lo bf16 state arrays.
__global__ __launch_bounds__(256) void proj_node(const float* __restrict__ X,
                                                 const float* __restrict__ W,
                                                 const float* __restrict__ B,
                                                 u16* __restrict__ Yh,
                                                 u16* __restrict__ Yl) {
  __shared__ float Ws[NDIM][HID];   // 22016 B, [k][j]
  __shared__ float Xs[32][NDIM];    // 5504 B,  [r][k]
  const int tid = threadIdx.x;
  const int row0 = blockIdx.x * 32;

  for (int i = tid; i < NDIM * (HID / 4); i += 256) {
    int k = i >> 5, j4 = (i & 31) << 2;
    *(float4*)&Ws[k][j4] = *(const float4*)&W[(size_t)k * HID + j4];
  }
  const float* Xb = X + (size_t)row0 * NDIM;
  for (int i = tid; i < 32 * NDIM; i += 256) ((float*)Xs)[i] = Xb[i];
  __syncthreads();

  const int cg = tid & 31, rg = tid >> 5;
  const int j0 = cg * 4, r0 = rg * 4;

  float acc[4][4];
#pragma unroll
  for (int rr = 0; rr < 4; ++rr)
#pragma unroll
    for (int cc = 0; cc < 4; ++cc) acc[rr][cc] = 0.f;

#pragma unroll 4
  for (int k = 0; k < NDIM; ++k) {
    const float4 w = *(const float4*)&Ws[k][j0];
    const float wv[4] = {w.x, w.y, w.z, w.w};
    const float xx[4] = {Xs[r0 + 0][k], Xs[r0 + 1][k], Xs[r0 + 2][k], Xs[r0 + 3][k]};
#pragma unroll
    for (int rr = 0; rr < 4; ++rr)
#pragma unroll
      for (int cc = 0; cc < 4; ++cc)
        acc[rr][cc] = fmaf(xx[rr], wv[cc], acc[rr][cc]);
  }

  const float4 bv = *(const float4*)&B[j0];
  const float bb[4] = {bv.x, bv.y, bv.z, bv.w};
#pragma unroll
  for (int rr = 0; rr < 4; ++rr) {
    int gr = row0 + r0 + rr;
    ushort4 ho, lo_;
    float v0 = acc[rr][0] + bb[0], v1 = acc[rr][1] + bb[1];
    float v2 = acc[rr][2] + bb[2], v3 = acc[rr][3] + bb[3];
    ho.x = f2bf(v0); lo_.x = f2bf(v0 - bf2f(ho.x));
    ho.y = f2bf(v1); lo_.y = f2bf(v1 - bf2f(ho.y));
    ho.z = f2bf(v2); lo_.z = f2bf(v2 - bf2f(ho.z));
    ho.w = f2bf(v3); lo_.w = f2bf(v3 - bf2f(ho.w));
    *(ushort4*)&Yh[(size_t)gr * HID + j0] = ho;
    *(ushort4*)&Yl[(size_t)gr * HID + j0] = lo_;
  }
}

// ---------------------------------------------------------------------------
// Weight prep: convert W [128][128] fp32 into MFMA B-fragment-ordered bf16
// hi/lo arrays. Packed layout per matrix (32768 u16 = 64 KB):
//   hi at [((ks*8+ct)*64+lane)*8 + e], lo at +16384
//   element = W[ks*32 + (lane>>4)*8 + e][ct*16 + (lane&15)]
// 16 matrices: n2c_wl(l=0..3), n2c_wr, c2n_wl, c2n_wr.
__global__ __launch_bounds__(256) void wprep(const float* __restrict__ n2c_wl,
                                             const float* __restrict__ n2c_wr,
                                             const float* __restrict__ c2n_wl,
                                             const float* __restrict__ c2n_wr,
                                             u16* __restrict__ wp) {
  int gid = blockIdx.x * 256 + threadIdx.x;  // 32768 total
  int lane = gid & 63;
  int t = gid >> 6;                          // 512: m(16) x ks(4) x ct(8)
  int ct = t & 7, ks = (t >> 3) & 3, m = t >> 5;
  const float* Wb;
  switch (m >> 2) {
    case 0: Wb = n2c_wl; break;
    case 1: Wb = n2c_wr; break;
    case 2: Wb = c2n_wl; break;
    default: Wb = c2n_wr; break;
  }
  Wb += (size_t)(m & 3) * HID * HID;
  const int kg = lane >> 4, c = ct * 16 + (lane & 15);
  u16 hi[8], lo[8];
#pragma unroll
  for (int e = 0; e < 8; ++e) {
    float v = Wb[(size_t)(ks * 32 + kg * 8 + e) * HID + c];
    hi[e] = f2bf(v);
    lo[e] = f2bf(v - bf2f(hi[e]));
  }
  size_t base = (size_t)m * 32768 + ((size_t)(ks * 8 + ct) * 64 + lane) * 8;
#pragma unroll
  for (int e = 0; e < 8; ++e) {
    wp[base + e] = hi[e];
    wp[base + 16384 + e] = lo[e];
  }
}

// ---------------------------------------------------------------------------
// MFMA GEMM: Y[r][j] = B[j] + sum_k X[r][k]*W[k][j]
// X given as hi/lo bf16 arrays [nrows][128]; W pre-packed in frag order.
// bf16x2 split, 3 products: Xh*Wh + Xh*Wl + Xl*Wh.
// Block = 64 rows (4 waves x 16 rows), each wave does 16x128 via 8 col-tiles.
// No LDS, no barriers. A-frags: 16B/lane frag-ready loads. B-frags: coalesced
// 16B/lane from L2-resident packed weights.
__global__ __launch_bounds__(256) void gemm_mfma(const u16* __restrict__ Xh,
                                                 const u16* __restrict__ Xl,
                                                 const u16* __restrict__ wp,
                                                 const float* __restrict__ B,
                                                 float* __restrict__ Y, int nrows) {
  const int tid = threadIdx.x;
  const int lane = tid & 63;
  const int wv = tid >> 6;
  const int row0 = blockIdx.x * 64 + wv * 16;
  const int ri = lane & 15;   // A row / D col within tile
  const int kg = lane >> 4;   // k-group
  int r = row0 + ri;
  r = r < nrows ? r : nrows - 1;
  const size_t xbase = (size_t)r * HID + kg * 8;

  bf16x8 Ah[4], Al[4];
#pragma unroll
  for (int ks = 0; ks < 4; ++ks) {
    Ah[ks] = *(const bf16x8*)&Xh[xbase + ks * 32];
    Al[ks] = *(const bf16x8*)&Xl[xbase + ks * 32];
  }

  f32x4 acc[8];
#pragma unroll
  for (int ct = 0; ct < 8; ++ct) acc[ct] = (f32x4){0.f, 0.f, 0.f, 0.f};

#pragma unroll
  for (int ks = 0; ks < 4; ++ks) {
    const u16* wb = wp + ((size_t)(ks * 8) * 64 + lane) * 8;
#pragma unroll
    for (int ct = 0; ct < 8; ++ct) {
      bf16x8 Bh = *(const bf16x8*)&wb[ct * 512];
      bf16x8 Bl = *(const bf16x8*)&wb[16384 + ct * 512];
      acc[ct] = __builtin_amdgcn_mfma_f32_16x16x32_bf16(Ah[ks], Bh, acc[ct], 0, 0, 0);
      acc[ct] = __builtin_amdgcn_mfma_f32_16x16x32_bf16(Al[ks], Bh, acc[ct], 0, 0, 0);
      acc[ct] = __builtin_amdgcn_mfma_f32_16x16x32_bf16(Ah[ks], Bl, acc[ct], 0, 0, 0);
    }
  }

  // D layout: col = lane&15, row = (lane>>4)*4 + reg  [verified m89/m91]
#pragma unroll
  for (int ct = 0; ct < 8; ++ct) {
    const float bias = B[ct * 16 + ri];
#pragma unroll
    for (int i = 0; i < 4; ++i) {
      int gr = row0 + kg * 4 + i;
      if (gr < nrows) Y[(size_t)gr * HID + ct * 16 + ri] = acc[ct][i] + bias;
    }
  }
}

// ---------------------------------------------------------------------------
// CSR build: histogram -> scan -> scatter
__global__ void hist_kernel(const int* __restrict__ dst, int* __restrict__ cnt) {
  int e = blockIdx.x * 256 + threadIdx.x;
  if (e < NEDGE) atomicAdd(&cnt[dst[e]], 1);
}

__global__ __launch_bounds__(256) void scan_blocks(const int* __restrict__ cnt,
                                                   int* __restrict__ pre,
                                                   int* __restrict__ bsum, int n) {
  __shared__ int sdata[256];
  const int b = blockIdx.x, t = threadIdx.x;
  const int base = b * 1024 + t * 4;
  int v[4], s = 0;
#pragma unroll
  for (int q = 0; q < 4; ++q) {
    int i = base + q;
    v[q] = (i < n) ? cnt[i] : 0;
    s += v[q];
  }
  sdata[t] = s;
  __syncthreads();
  for (int off = 1; off < 256; off <<= 1) {
    int y = (t >= off) ? sdata[t - off] : 0;
    __syncthreads();
    sdata[t] += y;
    __syncthreads();
  }
  int run = sdata[t] - s;  // exclusive prefix of thread sums
  if (t == 255) bsum[b] = sdata[255];
#pragma unroll
  for (int q = 0; q < 4; ++q) {
    int i = base + q;
    if (i < n) pre[i] = run;
    run += v[q];
  }
}

// single block; nb <= 128
__global__ __launch_bounds__(128) void scan_partials(int* __restrict__ bsum, int nb) {
  __shared__ int sd[128];
  int t = threadIdx.x;
  int v = (t < nb) ? bsum[t] : 0;
  sd[t] = v;
  __syncthreads();
  for (int off = 1; off < 128; off <<= 1) {
    int y = (t >= off) ? sd[t - off] : 0;
    __syncthreads();
    sd[t] += y;
    __syncthreads();
  }
  if (t < nb) bsum[t] = sd[t] - v;  // exclusive
}

__global__ void finalize_rowptr(const int* __restrict__ pre, const int* __restrict__ bsum,
                                int* __restrict__ rowptr, int n) {
  int i = blockIdx.x * 256 + threadIdx.x;
  if (i < n) rowptr[i] = pre[i] + bsum[i >> 10];
  if (i == 0) rowptr[n] = NEDGE;
}

__global__ void scatter_csr(const int* __restrict__ src, const int* __restrict__ dst,
                            const int* __restrict__ rowptr, int* __restrict__ cursor,
                            int* __restrict__ csr_src) {
  int e = blockIdx.x * 256 + threadIdx.x;
  if (e >= NEDGE) return;
  int d = dst[e];
  int p = atomicAdd(&cursor[d], 1);
  csr_src[rowptr[d] + p] = src[e];
}

// ---------------------------------------------------------------------------
// Fused per-dst GATv2: persistent, one wave (64 lanes x float2) per dst row.
// State x held as hi/lo bf16 arrays (xh/xlo); features fl/fr are fp32.
__global__ __launch_bounds__(256) void gat_dst(u16* __restrict__ xh,
                                               u16* __restrict__ xlo,
                                               const float* __restrict__ fl,   // [n_src][128]
                                               const float* __restrict__ fr,   // [n_dst][128]
                                               const int* __restrict__ rowptr,
                                               const int* __restrict__ csr_src,
                                               const float* __restrict__ att,  // [128]
                                               const float* __restrict__ bias,
                                               const float* __restrict__ g,
                                               const float* __restrict__ b,
                                               int n_dst) {
  const int wave = threadIdx.x >> 6;     // 0..3
  const int lane = threadIdx.x & 63;
  const int j = lane * 2;                // channels j, j+1; head = j>>5 = lane>>4

  const float2 attv = *(const float2*)&att[j];
  const float2 bias2 = *(const float2*)&bias[j];
  const float2 g2 = *(const float2*)&g[j];
  const float2 b2 = *(const float2*)&b[j];

  const int stride = gridDim.x * 4;
  for (int d = blockIdx.x * 4 + wave; d < n_dst; d += stride) {
    const float2 xrv = *(const float2*)&fr[(size_t)d * HID + j];
    const int e0 = rowptr[d], e1 = rowptr[d + 1];

    float2 acc = make_float2(0.f, 0.f);
    float den = 0.f;
    int idx = e0;
    for (; idx + 1 < e1; idx += 2) {
      const int s0 = csr_src[idx];
      const int s1 = csr_src[idx + 1];
      const float2 v0 = *(const float2*)&fl[(size_t)s0 * HID + j];
      const float2 v1 = *(const float2*)&fl[(size_t)s1 * HID + j];
      {
        float m0 = v0.x + xrv.x; m0 = m0 > 0.f ? m0 : 0.2f * m0;
        float m1 = v0.y + xrv.y; m1 = m1 > 0.f ? m1 : 0.2f * m1;
        float p = fmaf(attv.x, m0, attv.y * m1);
        p += __shfl_xor(p, 8); p += __shfl_xor(p, 4);
        p += __shfl_xor(p, 2); p += __shfl_xor(p, 1);
        float e_ = __expf(p);
        acc.x = fmaf(e_, v0.x, acc.x);
        acc.y = fmaf(e_, v0.y, acc.y);
        den += e_;
      }
      {
        float m0 = v1.x + xrv.x; m0 = m0 > 0.f ? m0 : 0.2f * m0;
        float m1 = v1.y + xrv.y; m1 = m1 > 0.f ? m1 : 0.2f * m1;
        float p = fmaf(attv.x, m0, attv.y * m1);
        p += __shfl_xor(p, 8); p += __shfl_xor(p, 4);
        p += __shfl_xor(p, 2); p += __shfl_xor(p, 1);
        float e_ = __expf(p);
        acc.x = fmaf(e_, v1.x, acc.x);
        acc.y = fmaf(e_, v1.y, acc.y);
        den += e_;
      }
    }
    if (idx < e1) {
      const int s0 = csr_src[idx];
      const float2 v0 = *(const float2*)&fl[(size_t)s0 * HID + j];
      float m0 = v0.x + xrv.x; m0 = m0 > 0.f ? m0 : 0.2f * m0;
      float m1 = v0.y + xrv.y; m1 = m1 > 0.f ? m1 : 0.2f * m1;
      float p = fmaf(attv.x, m0, attv.y * m1);
      p += __shfl_xor(p, 8); p += __shfl_xor(p, 4);
      p += __shfl_xor(p, 2); p += __shfl_xor(p, 1);
      float e_ = __expf(p);
      acc.x = fmaf(e_, v0.x, acc.x);
      acc.y = fmaf(e_, v0.y, acc.y);
      den += e_;
    }

    float2 outv = make_float2(0.f, 0.f);
    if (e1 > e0) { outv.x = acc.x / den; outv.y = acc.y / den; }

    // residual from hi/lo state
    const u32 hh = *(const u32*)&xh[(size_t)d * HID + j];
    const u32 ll = *(const u32*)&xlo[(size_t)d * HID + j];
    float vx = bf2f((u16)hh) + bf2f((u16)ll) + outv.x + bias2.x;
    float vy = bf2f((u16)(hh >> 16)) + bf2f((u16)(ll >> 16)) + outv.y + bias2.y;

    // LayerNorm across the wave (64 lanes x 2 channels = 128)
    float s1 = vx + vy;
    float s2 = vx * vx + vy * vy;
#pragma unroll
    for (int off = 32; off > 0; off >>= 1) {
      s1 += __shfl_xor(s1, off);
      s2 += __shfl_xor(s2, off);
    }
    const float mu = s1 * (1.0f / HID);
    const float var = s2 * (1.0f / HID) - mu * mu;
    const float inv = rsqrtf(var + 1e-5f);
    float ox = (vx - mu) * inv * g2.x + b2.x;
    float oy = (vy - mu) * inv * g2.y + b2.y;

    u16 h0 = f2bf(ox); u16 l0 = f2bf(ox - bf2f(h0));
    u16 h1 = f2bf(oy); u16 l1 = f2bf(oy - bf2f(h1));
    *(u32*)&xh[(size_t)d * HID + j] = (u32)h0 | ((u32)h1 << 16);
    *(u32*)&xlo[(size_t)d * HID + j] = (u32)l0 | ((u32)l1 << 16);
  }
}

// ---------------------------------------------------------------------------
__global__ void colsum(const u16* __restrict__ xh, const u16* __restrict__ xlo,
                       float* __restrict__ acc) {
  int j = threadIdx.x;  // 128 threads
  int per = (NCLS + gridDim.x - 1) / gridDim.x;
  int r0 = blockIdx.x * per;
  int r1 = min(r0 + per, NCLS);
  float s = 0.f;
  for (int r = r0; r < r1; ++r)
    s += bf2f(xh[(size_t)r * HID + j]) + bf2f(xlo[(size_t)r * HID + j]);
  atomicAdd(&acc[j], s);
}

__global__ void final_out(const float* __restrict__ acc, float* __restrict__ out) {
  int j = threadIdx.x;
  out[j] = acc[j] * (1.0f / NCLS);
}

// ---------------------------------------------------------------------------
extern "C" void kernel_launch(void* const* d_in, const int* in_sizes, int n_in,
                              void* d_out, int out_size, void* d_ws, size_t ws_size,
                              hipStream_t stream) {
  (void)in_sizes; (void)n_in; (void)out_size; (void)ws_size;
  const float* x_node     = (const float*)d_in[0];
  const float* x_class    = (const float*)d_in[1];
  const int* member_src   = (const int*)d_in[2];
  const int* member_dst   = (const int*)d_in[3];
  const int* contains_src = (const int*)d_in[4];
  const int* contains_dst = (const int*)d_in[5];
  const float* npw = (const float*)d_in[6];
  const float* npb = (const float*)d_in[7];
  const float* cpw = (const float*)d_in[8];
  const float* cpb = (const float*)d_in[9];
  const float* n2c_wl   = (const float*)d_in[10];
  const float* n2c_bl   = (const float*)d_in[11];
  const float* n2c_wr   = (const float*)d_in[12];
  const float* n2c_br   = (const float*)d_in[13];
  const float* n2c_att  = (const float*)d_in[14];
  const float* n2c_bias = (const float*)d_in[15];
  const float* c2n_wl   = (const float*)d_in[16];
  const float* c2n_bl   = (const float*)d_in[17];
  const float* c2n_wr   = (const float*)d_in[18];
  const float* c2n_br   = (const float*)d_in[19];
  const float* c2n_att  = (const float*)d_in[20];
  const float* c2n_bias = (const float*)d_in[21];
  const float* ln_cg = (const float*)d_in[22];
  const float* ln_cb = (const float*)d_in[23];
  const float* ln_ng = (const float*)d_in[24];
  const float* ln_nb = (const float*)d_in[25];

  // workspace layout
  u16* xnh = (u16*)d_ws;                             // NNODE*128 u16
  u16* xnl = xnh + (size_t)NNODE * HID;              // NNODE*128
  u16* xch = xnl + (size_t)NNODE * HID;              // NCLS*128
  u16* xcl = xch + (size_t)NCLS * HID;               // NCLS*128
  float* fl = (float*)(xcl + (size_t)NCLS * HID);    // NNODE*128 f32
  float* fr = fl + (size_t)NNODE * HID;              // NNODE*128 f32
  float* accb = fr + (size_t)NNODE * HID;            // 128
  int* rowptr_c = (int*)(accb + 128);                // NCLS+1
  int* csr_c    = rowptr_c + (NCLS + 1);             // NEDGE
  int* rowptr_n = csr_c + NEDGE;                     // NNODE+1
  int* csr_n    = rowptr_n + (NNODE + 1);            // NEDGE
  int* cnt      = csr_n + NEDGE;                     // NNODE
  int* cursor   = cnt + NNODE;                       // NNODE
  int* pre      = cursor + NNODE;                    // NNODE
  int* bsum     = pre + NNODE;                       // 128
  // packed weights overlay the dead cnt buffer after CSR build:
  // 16 matrices x 32768 u16 = 524288 u16 = 1 MB <= NNODE ints (1.6 MB)
  u16* wp = (u16*)cnt;

  const int EB = (NEDGE + 255) / 256;
  const int GAT_BLOCKS = 2048;  // persistent: 2048 blocks x 4 waves

  // ---- initial projections (write hi/lo state) ----
  proj_node<<<NNODE / 32, 256, 0, stream>>>(x_node, npw, npb, xnh, xnl);
  proj_kernel<<<(NCLS * HID + 255) / 256, 256, 0, stream>>>(x_class, cpw, cpb, xch, xcl, NCLS, CDIM);

  // ---- CSR build: member (dst=class) ----
  hipMemsetAsync(cnt, 0, NCLS * sizeof(int), stream);
  hipMemsetAsync(cursor, 0, NCLS * sizeof(int), stream);
  hist_kernel<<<EB, 256, 0, stream>>>(member_dst, cnt);
  scan_blocks<<<(NCLS + 1023) / 1024, 256, 0, stream>>>(cnt, pre, bsum, NCLS);
  scan_partials<<<1, 128, 0, stream>>>(bsum, (NCLS + 1023) / 1024);
  finalize_rowptr<<<(NCLS + 255) / 256, 256, 0, stream>>>(pre, bsum, rowptr_c, NCLS);
  scatter_csr<<<EB, 256, 0, stream>>>(member_src, member_dst, rowptr_c, cursor, csr_c);

  // ---- CSR build: contains (dst=node) ----
  hipMemsetAsync(cnt, 0, NNODE * sizeof(int), stream);
  hipMemsetAsync(cursor, 0, NNODE * sizeof(int), stream);
  hist_kernel<<<EB, 256, 0, stream>>>(contains_dst, cnt);
  scan_blocks<<<(NNODE + 1023) / 1024, 256, 0, stream>>>(cnt, pre, bsum, NNODE);
  scan_partials<<<1, 128, 0, stream>>>(bsum, (NNODE + 1023) / 1024);
  finalize_rowptr<<<(NNODE + 255) / 256, 256, 0, stream>>>(pre, bsum, rowptr_n, NNODE);
  scatter_csr<<<EB, 256, 0, stream>>>(contains_src, contains_dst, rowptr_n, cursor, csr_n);

  // ---- pack weights into MFMA frag order (cnt is dead now) ----
  wprep<<<128, 256, 0, stream>>>(n2c_wl, n2c_wr, c2n_wl, c2n_wr, wp);

  const int GB_N = (NNODE + 63) / 64;
  const int GB_C = (NCLS + 63) / 64;

  // ---- layers ----
  for (int l = 0; l < NLAY; ++l) {
    // n2c: src=xn (NNODE), dst=xc (NCLS)
    gemm_mfma<<<GB_N, 256, 0, stream>>>(xnh, xnl, wp + (size_t)(0 + l) * 32768,
                                        n2c_bl + l * HID, fl, NNODE);
    gemm_mfma<<<GB_C, 256, 0, stream>>>(xch, xcl, wp + (size_t)(4 + l) * 32768,
                                        n2c_br + l * HID, fr, NCLS);
    gat_dst<<<GAT_BLOCKS, 256, 0, stream>>>(xch, xcl, fl, fr, rowptr_c, csr_c,
                                            n2c_att + l * HID, n2c_bias + l * HID,
                                            ln_cg + l * HID, ln_cb + l * HID, NCLS);

    // c2n: src=xc (NCLS), dst=xn (NNODE)
    gemm_mfma<<<GB_C, 256, 0, stream>>>(xch, xcl, wp + (size_t)(8 + l) * 32768,
                                        c2n_bl + l * HID, fl, NCLS);
    gemm_mfma<<<GB_N, 256, 0, stream>>>(xnh, xnl, wp + (size_t)(12 + l) * 32768,
                                        c2n_br + l * HID, fr, NNODE);
    gat_dst<<<GAT_BLOCKS, 256, 0, stream>>>(xnh, xnl, fl, fr, rowptr_n, csr_n,
                                            c2n_att + l * HID, c2n_bias + l * HID,
                                            ln_ng + l * HID, ln_nb + l * HID, NNODE);
  }

  hipMemsetAsync(accb, 0, HID * sizeof(float), stream);
  colsum<<<256, HID, 0, stream>>>(xch, xcl, accb);
  final_out<<<1, HID, 0, stream>>>(accb, (float*)d_out);
}